// Round 8
// baseline (3985.501 us; speedup 1.0000x reference)
//
#include <hip/hip_runtime.h>

// FPS: input [8, 65536, 3] f32 -> (idx [8,1024] as f32 values, sampled [8,1024,3] f32)
// concatenated flat in d_out.
//
// Latency-bound sequential argmax (1023 rounds). 8 WGs/batch (CONTIGUOUS
// blocks 8b..8b+7 -> same XCD, R6-verified), 1024 thr/WG, 8 points/thread in
// REGISTERS. Per round:
//  - distance update (uncontracted fp32, reference order -> bit-exact)
//  - stage1: 6-level 32-bit fp32 max butterfly + ballot argmax (unique-max
//    fast path; rare ties resolved exactly: smallest (i,lane) = smallest
//    global index = numpy argmax first-occurrence). Winner lane -> LDS red[].
//  - ONE __syncthreads.
//  - stage2 (wave0): 4-level 32-bit max butterfly over 16 wave candidates +
//    ballot (ties: max(65535-n) among tied -> smallest n); winner lane
//    publishes self-tagged record (3x 8B, tag in low16 of each; parity dbuf)
//    via fire-and-forget sc0 stores -> XCD-shared L2 (copy L).
//  - wave15: duplicate stage2, mirrors record to copy I with relaxed
//    agent-scope atomics (IF-visible fallback), then waits on a round-tagged
//    LDS flag (release/acquire) for the centroid from wave0 — never touches
//    vmcnt, so its IF store-acks hurt nothing.
//  - waves 0..14: ALL lanes poll copy L (lane&7's line) with sc0 loads;
//    256-spin timeout -> permanent per-lane fallback to agent-scope polls of
//    copy I (placement-independent correctness; stale L2 lines can't fake a
//    future tag; per-word self-tags make mixed-age words harmless).
//  - stage3: 3-level 32-bit max butterfly + ballot -> winner record src;
//    n2/xyz via __shfl from lane src. Every lane self-decodes the centroid:
//    NO second barrier, no LDS broadcast (except the wave15 flag handoff).
// Slot reuse at t+2 ordered by barrier1-only tag transitivity: publish(t+2)
// follows barrier1(t+2) follows all own waves passing poll(t+1) follows all
// WGs' tags(t+1) follows those WGs' waves finishing their slot(t) reads.

#define NB    8
#define NPTS  65536
#define NSAMP 1024
#define WPB   8      // workgroups per batch
#define TPB   1024   // threads per workgroup
#define PPT   8      // points per thread (WPB*TPB*PPT == NPTS)
#define RECQ  16     // 16 ull = 128 B per record line

typedef unsigned long long ull;

// 3x 8B loads from one 128B line, L1-bypass (sc0) -> reads the XCD L2.
__device__ __forceinline__ void ld3_sc0(const ull* p, ull& a, ull& b, ull& c) {
  asm volatile(
      "global_load_dwordx2 %0, %3, off sc0\n\t"
      "global_load_dwordx2 %1, %3, off offset:8 sc0\n\t"
      "global_load_dwordx2 %2, %3, off offset:16 sc0\n\t"
      "s_waitcnt vmcnt(0)"
      : "=&v"(a), "=&v"(b), "=&v"(c) : "v"(p) : "memory");
}

// 3x 8B stores to one 128B line, fire-and-forget (write-through to XCD L2).
__device__ __forceinline__ void st3_sc0(ull* p, ull a, ull b, ull c) {
  asm volatile(
      "global_store_dwordx2 %3, %0, off sc0\n\t"
      "global_store_dwordx2 %3, %1, off offset:8 sc0\n\t"
      "global_store_dwordx2 %3, %2, off offset:16 sc0"
      :: "v"(a), "v"(b), "v"(c), "v"(p) : "memory");
}

__global__ __launch_bounds__(TPB, 4)
void fps_kernel(const float* __restrict__ pts, float* __restrict__ out,
                ull* __restrict__ ws) {
  const int wg   = blockIdx.x;   // 0..63
  const int b    = wg >> 3;      // batch: CONTIGUOUS blocks 8b..8b+7 (one XCD)
  const int w    = wg & 7;       // wg within batch, 0..7
  const int tid  = threadIdx.x;
  const int lane = tid & 63;
  const int wave = tid >> 6;     // 0..15

  const float* p = pts + (size_t)b * NPTS * 3;

  float px[PPT], py[PPT], pz[PPT], md[PPT];
#pragma unroll
  for (int i = 0; i < PPT; ++i) {
    const int n = w * (TPB * PPT) + i * TPB + tid;
    px[i] = p[3 * n + 0];
    py[i] = p[3 * n + 1];
    pz[i] = p[3 * n + 2];
    md[i] = 1e10f;               // BIG, matches reference init
  }

  float cx = p[0], cy = p[1], cz = p[2];   // first pick is index 0

  // ws (ull): [0 .. 2048)    copy L (sc0/L2): batch b at b*256, 2 par x 8 wg x 16
  //           [2048 .. 4096) copy I (agent/IF): same layout
  ull* baseL = ws + (size_t)b * (2 * WPB * RECQ);
  ull* baseI = ws + (size_t)NB * (2 * WPB * RECQ) + (size_t)b * (2 * WPB * RECQ);

  float* out_idx = out + (size_t)b * NSAMP;
  float* out_smp = out + (size_t)NB * NSAMP + (size_t)b * NSAMP * 3;

  if (w == 0 && tid == 0) {
    out_idx[0] = 0.0f;
    out_smp[0] = cx; out_smp[1] = cy; out_smp[2] = cz;
  }

  __shared__ unsigned red[16][5];  // per-wave {dist_bits, n, x, y, z}
  __shared__ float bcv[3];         // centroid handoff for wave15
  __shared__ int flag;             // round-tagged handoff flag

  if (wave == 15 && lane == 0) flag = 0;  // in-order DS pipe: precedes wave15's reads

  bool useIF = false;              // per-lane permanent fallback to IF polling

  for (int t = 0; t < NSAMP - 1; ++t) {
    // ---- tail: local distance update + thread-local best ----
    float bv = -1.0f; int bi = 0; float bx = 0.f, by = 0.f, bz = 0.f;
#pragma unroll
    for (int i = 0; i < PPT; ++i) {
      const float dx = __fsub_rn(px[i], cx);
      const float dy = __fsub_rn(py[i], cy);
      const float dz = __fsub_rn(pz[i], cz);
      const float d  = __fadd_rn(__fadd_rn(__fmul_rn(dx, dx), __fmul_rn(dy, dy)),
                                 __fmul_rn(dz, dz));
      const float m = fminf(md[i], d);
      md[i] = m;
      if (m > bv) {  // strict > keeps earliest i (smallest n) on ties
        bv = m; bi = i;
        bx = px[i]; by = py[i]; bz = pz[i];
      }
    }

    // ---- stage1: 32-bit fp32 max butterfly + ballot argmax ----
    float maxd = bv;
#pragma unroll
    for (int s = 1; s < 64; s <<= 1) {
      const float o = __shfl_xor(maxd, s, 64);
      maxd = fmaxf(maxd, o);
    }
    const bool tied = (bv == maxd);           // dist finite, no NaN
    const ull bal0 = __ballot(tied);
    int wlane;
    if (__popcll(bal0) == 1) {
      wlane = __ffsll(bal0) - 1;              // unique max (typical)
    } else {
      // exact first-occurrence: smallest (bi, lane) among tied lanes
      ull sel = 0;
#pragma unroll
      for (int ii = 0; ii < PPT; ++ii) {
        const ull bb = __ballot(tied && (bi == ii));
        const bool take = (sel == 0) && (bb != 0);
        sel = take ? bb : sel;
      }
      wlane = __ffsll(sel) - 1;
    }
    if (lane == wlane) {
      red[wave][0] = __float_as_uint(bv);
      red[wave][1] = (unsigned)(w * (TPB * PPT) + bi * TPB + tid);
      red[wave][2] = __float_as_uint(bx);
      red[wave][3] = __float_as_uint(by);
      red[wave][4] = __float_as_uint(bz);
    }
    __syncthreads();  // the ONLY barrier per round

    const ull tag = (ull)(unsigned)(t + 1);   // 1..1023; 0xAAAA poison never matches
    const int par = t & 1;

    if (wave == 15) {
      // ---- stage2 (duplicate): mirror publish to copy I (IF fallback) ----
      const int e = lane & 15;
      const unsigned d2 = red[e][0];
      const unsigned nn = red[e][1];
      unsigned m2 = d2;
#pragma unroll
      for (int s = 1; s < 16; s <<= 1) {
        const unsigned o = __shfl_xor(m2, s, 64);
        m2 = o > m2 ? o : m2;
      }
      const ull bb = __ballot(d2 == m2) & 0xFFFFull;
      int ewin;
      if (__popcll(bb) == 1) {
        ewin = __ffsll(bb) - 1;
      } else {
        const unsigned v = (d2 == m2) ? (65535u - nn) : 0u;   // max -> smallest n
        unsigned mv = v;
#pragma unroll
        for (int s = 1; s < 16; s <<= 1) {
          const unsigned o = __shfl_xor(mv, s, 64);
          mv = o > mv ? o : mv;
        }
        const ull b2 = __ballot((d2 == m2) && (v == mv)) & 0xFFFFull;
        ewin = __ffsll(b2) - 1;
      }
      if (lane == ewin) {
        const ull k2 = ((ull)d2 << 16) | (ull)(65535u - nn);
        const unsigned xb = red[e][2], yb = red[e][3], zb = red[e][4];
        const ull w0 = (k2 << 16) | tag;
        const ull w1 = ((ull)xb << 32) | ((ull)(yb >> 16) << 16) | tag;
        const ull w2 = ((ull)(yb & 0xFFFFu) << 48) | ((ull)zb << 16) | tag;
        ull* recI = baseI + (size_t)(par * WPB + w) * RECQ;
        __hip_atomic_store(recI + 0, w0, __ATOMIC_RELAXED, __HIP_MEMORY_SCOPE_AGENT);
        __hip_atomic_store(recI + 1, w1, __ATOMIC_RELAXED, __HIP_MEMORY_SCOPE_AGENT);
        __hip_atomic_store(recI + 2, w2, __ATOMIC_RELAXED, __HIP_MEMORY_SCOPE_AGENT);
      }
      // ---- centroid handoff from wave0 (LDS only; no vmcnt involvement) ----
      while (__hip_atomic_load(&flag, __ATOMIC_ACQUIRE,
                               __HIP_MEMORY_SCOPE_WORKGROUP) != (int)(t + 1)) {}
      cx = bcv[0]; cy = bcv[1]; cz = bcv[2];
    } else {
      if (wave == 0) {
        // ---- stage2: select WG winner, publish copy L (sc0 -> shared L2) ----
        const int e = lane & 15;
        const unsigned d2 = red[e][0];
        const unsigned nn = red[e][1];
        unsigned m2 = d2;
#pragma unroll
        for (int s = 1; s < 16; s <<= 1) {
          const unsigned o = __shfl_xor(m2, s, 64);
          m2 = o > m2 ? o : m2;
        }
        const ull bb = __ballot(d2 == m2) & 0xFFFFull;
        int ewin;
        if (__popcll(bb) == 1) {
          ewin = __ffsll(bb) - 1;
        } else {
          const unsigned v = (d2 == m2) ? (65535u - nn) : 0u;
          unsigned mv = v;
#pragma unroll
          for (int s = 1; s < 16; s <<= 1) {
            const unsigned o = __shfl_xor(mv, s, 64);
            mv = o > mv ? o : mv;
          }
          const ull b2 = __ballot((d2 == m2) && (v == mv)) & 0xFFFFull;
          ewin = __ffsll(b2) - 1;
        }
        if (lane == ewin) {
          const ull k2 = ((ull)d2 << 16) | (ull)(65535u - nn);
          const unsigned xb = red[e][2], yb = red[e][3], zb = red[e][4];
          const ull w0 = (k2 << 16) | tag;
          const ull w1 = ((ull)xb << 32) | ((ull)(yb >> 16) << 16) | tag;
          const ull w2 = ((ull)(yb & 0xFFFFu) << 48) | ((ull)zb << 16) | tag;
          st3_sc0(baseL + (size_t)(par * WPB + w) * RECQ, w0, w1, w2);
        }
      }

      // ---- poll: every lane loads record lane&7 (L2 copy; timeout -> IF) ----
      ull r0 = 0, r1 = 0, r2 = 0;
      {
        const size_t roff = (size_t)(par * WPB + (lane & 7)) * RECQ;
        const ull* recL = baseL + roff;
        const ull* recI = baseI + roff;
        bool done = false;
        int spins = 0;
        for (;;) {
          if (!done) {
            if (!useIF) {
              ld3_sc0(recL, r0, r1, r2);
            } else {
              r0 = __hip_atomic_load(recI + 0, __ATOMIC_RELAXED, __HIP_MEMORY_SCOPE_AGENT);
              r1 = __hip_atomic_load(recI + 1, __ATOMIC_RELAXED, __HIP_MEMORY_SCOPE_AGENT);
              r2 = __hip_atomic_load(recI + 2, __ATOMIC_RELAXED, __HIP_MEMORY_SCOPE_AGENT);
            }
            done = ((r0 & 0xFFFFull) == tag) & ((r1 & 0xFFFFull) == tag) &
                   ((r2 & 0xFFFFull) == tag);
            if (!done && !useIF && ++spins > 256) useIF = true;  // cross-XCD fallback
          }
          if (__all(done)) break;
          if (useIF) __builtin_amdgcn_s_sleep(1);
        }
      }

      // ---- stage3: 3-level 32-bit max butterfly + ballot -> winner src ----
      const unsigned d3  = (unsigned)(r0 >> 32);            // dist bits
      const unsigned lnv = (unsigned)((r0 >> 16) & 0xFFFFull);  // 65535-n
      unsigned m3 = d3;
#pragma unroll
      for (int s = 1; s < 8; s <<= 1) {
        const unsigned o = __shfl_xor(m3, s, 64);
        m3 = o > m3 ? o : m3;
      }
      const ull b3 = __ballot(d3 == m3) & 0xFFull;
      int src;
      if (__popcll(b3) == 1) {
        src = __ffsll(b3) - 1;
      } else {
        const unsigned v = (d3 == m3) ? lnv : 0u;           // max -> smallest n
        unsigned mv = v;
#pragma unroll
        for (int s = 1; s < 8; s <<= 1) {
          const unsigned o = __shfl_xor(mv, s, 64);
          mv = o > mv ? o : mv;
        }
        const ull b4 = __ballot((d3 == m3) && (v == mv)) & 0xFFull;
        src = __ffsll(b4) - 1;
      }
      // decode own record, fetch winner's fields from lane src
      const float xx = __uint_as_float((unsigned)(r1 >> 32));
      const float yy = __uint_as_float(((unsigned)((r1 >> 16) & 0xFFFFull) << 16) |
                                       (unsigned)(r2 >> 48));
      const float zz = __uint_as_float((unsigned)((r2 >> 16) & 0xFFFFFFFFull));
      const int n2   = 65535 - (int)__shfl(lnv, src, 64);
      const float wx = __shfl(xx, src, 64);
      const float wy = __shfl(yy, src, 64);
      const float wz = __shfl(zz, src, 64);
      if (wave == 0 && lane == 0) {
        bcv[0] = wx; bcv[1] = wy; bcv[2] = wz;
        __hip_atomic_store(&flag, (int)(t + 1), __ATOMIC_RELEASE,
                           __HIP_MEMORY_SCOPE_WORKGROUP);
        if (w == 0) {
          out_idx[t + 1] = (float)n2;           // exact in fp32
          out_smp[(t + 1) * 3 + 0] = wx;
          out_smp[(t + 1) * 3 + 1] = wy;
          out_smp[(t + 1) * 3 + 2] = wz;
        }
      }
      cx = wx; cy = wy; cz = wz;
    }
  }
}

extern "C" void kernel_launch(void* const* d_in, const int* in_sizes, int n_in,
                              void* d_out, int out_size, void* d_ws, size_t ws_size,
                              hipStream_t stream) {
  (void)in_sizes; (void)n_in; (void)out_size; (void)ws_size;
  const float* pts = (const float*)d_in[0];
  float* out = (float*)d_out;
  ull* ws = (ull*)d_ws;
  fps_kernel<<<dim3(NB * WPB), dim3(TPB), 0, stream>>>(pts, out, ws);
}

// Round 9
// 2513.046 us; speedup vs baseline: 1.5859x; 1.5859x over previous
//
#include <hip/hip_runtime.h>

// FPS: input [8, 65536, 3] f32 -> (idx [8,1024] as f32 values, sampled [8,1024,3] f32)
// concatenated flat in d_out.
//
// R9 = R7 skeleton (PROVEN fastest: two barriers, wave0-only polling of the
// XCD-L2 copy, wave1 mirrors to IF) + R8's faster reduces (32-bit fp32 max
// butterflies + ballot argmax instead of 64-bit key butterflies).
//
// Latency-bound sequential argmax (1023 rounds). 8 WGs/batch (CONTIGUOUS
// blocks 8b..8b+7 -> same XCD, R6-verified), 1024 thr/WG, 8 points/thread in
// REGISTERS. Per round:
//  - distance update (uncontracted fp32, reference order -> bit-exact)
//  - stage1: 6-level fp32 max butterfly + ballot argmax (unique-max fast
//    path; ties resolved exactly to smallest global index = numpy argmax
//    first-occurrence). Winner lane -> LDS red[]. barrier1.
//  - stage2 (wave0): 4-level fp32 max butterfly over 16 wave candidates +
//    ballot (ties: max(65535-n) -> smallest n); winner lane publishes
//    self-tagged record (3x 8B words, round tag in low16 of each; parity
//    double-buffered) via fire-and-forget sc0 stores -> XCD-shared L2.
//  - wave1: duplicate stage2, mirrors record to copy I with relaxed
//    agent-scope atomics (IF fallback) — off wave0's vmcnt path.
//  - wave0 lanes 0..7 poll copy L with sc0 loads; 256-spin timeout ->
//    permanent per-lane fallback to agent-scope polls of copy I
//    (placement-independent correctness: stale L2 lines can't fake a future
//    tag; per-word self-tags make mixed-age words harmless).
//  - stage3: 3-level fp32 max butterfly + ballot over the 8 records ->
//    winner lane src; n2/xyz fetched via __shfl from src; lane0 writes LDS
//    bc[] (+ d_out if w==0). barrier2; all threads read the new centroid.
// Slot reuse at t+2 ordered by tag transitivity through barrier2.

#define NB    8
#define NPTS  65536
#define NSAMP 1024
#define WPB   8      // workgroups per batch
#define TPB   1024   // threads per workgroup
#define PPT   8      // points per thread (WPB*TPB*PPT == NPTS)
#define RECQ  16     // 16 ull = 128 B per record line

typedef unsigned long long ull;

// 3x 8B loads from one 128B line, L1-bypass (sc0) -> reads the XCD L2.
__device__ __forceinline__ void ld3_sc0(const ull* p, ull& a, ull& b, ull& c) {
  asm volatile(
      "global_load_dwordx2 %0, %3, off sc0\n\t"
      "global_load_dwordx2 %1, %3, off offset:8 sc0\n\t"
      "global_load_dwordx2 %2, %3, off offset:16 sc0\n\t"
      "s_waitcnt vmcnt(0)"
      : "=&v"(a), "=&v"(b), "=&v"(c) : "v"(p) : "memory");
}

// 3x 8B stores to one 128B line, fire-and-forget (write-through to XCD L2).
__device__ __forceinline__ void st3_sc0(ull* p, ull a, ull b, ull c) {
  asm volatile(
      "global_store_dwordx2 %3, %0, off sc0\n\t"
      "global_store_dwordx2 %3, %1, off offset:8 sc0\n\t"
      "global_store_dwordx2 %3, %2, off offset:16 sc0"
      :: "v"(a), "v"(b), "v"(c), "v"(p) : "memory");
}

__global__ __launch_bounds__(TPB, 4)
void fps_kernel(const float* __restrict__ pts, float* __restrict__ out,
                ull* __restrict__ ws) {
  const int wg   = blockIdx.x;   // 0..63
  const int b    = wg >> 3;      // batch: CONTIGUOUS blocks 8b..8b+7 (one XCD)
  const int w    = wg & 7;       // wg within batch, 0..7
  const int tid  = threadIdx.x;
  const int lane = tid & 63;
  const int wave = tid >> 6;     // 0..15

  const float* p = pts + (size_t)b * NPTS * 3;

  float px[PPT], py[PPT], pz[PPT], md[PPT];
#pragma unroll
  for (int i = 0; i < PPT; ++i) {
    const int n = w * (TPB * PPT) + i * TPB + tid;
    px[i] = p[3 * n + 0];
    py[i] = p[3 * n + 1];
    pz[i] = p[3 * n + 2];
    md[i] = 1e10f;               // BIG, matches reference init
  }

  float cx = p[0], cy = p[1], cz = p[2];   // first pick is index 0

  // ws (ull): [0 .. 2048)    copy L (sc0/L2): batch b at b*256, 2 par x 8 wg x 16
  //           [2048 .. 4096) copy I (agent/IF): same layout
  ull* baseL = ws + (size_t)b * (2 * WPB * RECQ);
  ull* baseI = ws + (size_t)NB * (2 * WPB * RECQ) + (size_t)b * (2 * WPB * RECQ);

  float* out_idx = out + (size_t)b * NSAMP;
  float* out_smp = out + (size_t)NB * NSAMP + (size_t)b * NSAMP * 3;

  if (w == 0 && tid == 0) {
    out_idx[0] = 0.0f;
    out_smp[0] = cx; out_smp[1] = cy; out_smp[2] = cz;
  }

  __shared__ unsigned red[16][5];  // per-wave {dist_bits, n, x, y, z}
  __shared__ float bc[3];          // winner xyz broadcast

  bool useIF = false;              // per-lane permanent fallback to IF polling

  for (int t = 0; t < NSAMP - 1; ++t) {
    // ---- local distance update + thread-local best ----
    float bv = -1.0f; int bi = 0; float bx = 0.f, by = 0.f, bz = 0.f;
#pragma unroll
    for (int i = 0; i < PPT; ++i) {
      const float dx = __fsub_rn(px[i], cx);
      const float dy = __fsub_rn(py[i], cy);
      const float dz = __fsub_rn(pz[i], cz);
      const float d  = __fadd_rn(__fadd_rn(__fmul_rn(dx, dx), __fmul_rn(dy, dy)),
                                 __fmul_rn(dz, dz));
      const float m = fminf(md[i], d);
      md[i] = m;
      if (m > bv) {  // strict > keeps earliest i (smallest n) on ties
        bv = m; bi = i;
        bx = px[i]; by = py[i]; bz = pz[i];
      }
    }

    // ---- stage1: fp32 max butterfly + ballot argmax ----
    float maxd = bv;
#pragma unroll
    for (int s = 1; s < 64; s <<= 1) {
      const float o = __shfl_xor(maxd, s, 64);
      maxd = fmaxf(maxd, o);
    }
    const bool tied = (bv == maxd);           // dist finite, no NaN
    const ull bal0 = __ballot(tied);
    int wlane;
    if (__popcll(bal0) == 1) {
      wlane = __ffsll(bal0) - 1;              // unique max (typical)
    } else {
      // exact first-occurrence: smallest (bi, lane) among tied lanes
      ull sel = 0;
#pragma unroll
      for (int ii = 0; ii < PPT; ++ii) {
        const ull bb = __ballot(tied && (bi == ii));
        const bool take = (sel == 0) && (bb != 0);
        sel = take ? bb : sel;
      }
      wlane = __ffsll(sel) - 1;
    }
    if (lane == wlane) {
      red[wave][0] = __float_as_uint(bv);
      red[wave][1] = (unsigned)(w * (TPB * PPT) + bi * TPB + tid);
      red[wave][2] = __float_as_uint(bx);
      red[wave][3] = __float_as_uint(by);
      red[wave][4] = __float_as_uint(bz);
    }
    __syncthreads();  // barrier1

    const ull tag = (ull)(unsigned)(t + 1);   // 1..1023; 0xAAAA poison never matches
    const int par = t & 1;

    if (wave == 0) {
      // ---- stage2: 16-cand reduce (32-bit + ballot); publish copy L ----
      const int e = lane & 15;
      const unsigned d2 = red[e][0];
      const unsigned nn = red[e][1];
      unsigned m2 = d2;
#pragma unroll
      for (int s = 1; s < 16; s <<= 1) {
        const unsigned o = __shfl_xor(m2, s, 64);
        m2 = o > m2 ? o : m2;
      }
      const ull bb = __ballot(d2 == m2) & 0xFFFFull;
      int ewin;
      if (__popcll(bb) == 1) {
        ewin = __ffsll(bb) - 1;
      } else {
        const unsigned v = (d2 == m2) ? (65535u - nn) : 0u;   // max -> smallest n
        unsigned mv = v;
#pragma unroll
        for (int s = 1; s < 16; s <<= 1) {
          const unsigned o = __shfl_xor(mv, s, 64);
          mv = o > mv ? o : mv;
        }
        const ull b2 = __ballot((d2 == m2) && (v == mv)) & 0xFFFFull;
        ewin = __ffsll(b2) - 1;
      }
      if (lane == ewin) {
        const ull k2 = ((ull)d2 << 16) | (ull)(65535u - nn);
        const unsigned xb = red[e][2], yb = red[e][3], zb = red[e][4];
        const ull w0 = (k2 << 16) | tag;
        const ull w1 = ((ull)xb << 32) | ((ull)(yb >> 16) << 16) | tag;
        const ull w2 = ((ull)(yb & 0xFFFFu) << 48) | ((ull)zb << 16) | tag;
        st3_sc0(baseL + (size_t)(par * WPB + w) * RECQ, w0, w1, w2);
      }

      // ---- lanes 0..7 poll (L2 copy, 256-spin timeout -> IF copy) ----
      const size_t roff = (size_t)(par * WPB + (lane & 7)) * RECQ;
      const ull* recL = baseL + roff;
      const ull* recI = baseI + roff;
      const bool mine = (lane < WPB);
      bool done = !mine;
      ull r0 = 0, r1 = 0, r2 = 0;
      int spins = 0;
      for (;;) {
        if (!done) {
          if (!useIF) {
            ld3_sc0(recL, r0, r1, r2);
          } else {
            r0 = __hip_atomic_load(recI + 0, __ATOMIC_RELAXED, __HIP_MEMORY_SCOPE_AGENT);
            r1 = __hip_atomic_load(recI + 1, __ATOMIC_RELAXED, __HIP_MEMORY_SCOPE_AGENT);
            r2 = __hip_atomic_load(recI + 2, __ATOMIC_RELAXED, __HIP_MEMORY_SCOPE_AGENT);
          }
          done = ((r0 & 0xFFFFull) == tag) & ((r1 & 0xFFFFull) == tag) &
                 ((r2 & 0xFFFFull) == tag);
          if (!done && !useIF && ++spins > 256) useIF = true;  // cross-XCD fallback
        }
        if (__all(done)) break;
        if (useIF) __builtin_amdgcn_s_sleep(1);
      }

      // ---- stage3: 8-record reduce (32-bit + ballot) -> winner lane src ----
      const unsigned d3  = (unsigned)(r0 >> 32);                 // dist bits
      const unsigned lnv = (unsigned)((r0 >> 16) & 0xFFFFull);   // 65535-n
      unsigned m3 = d3;
#pragma unroll
      for (int s = 1; s < 8; s <<= 1) {
        const unsigned o = __shfl_xor(m3, s, 64);
        m3 = o > m3 ? o : m3;
      }
      const ull b3 = __ballot(d3 == m3) & 0xFFull;
      int src;
      if (__popcll(b3) == 1) {
        src = __ffsll(b3) - 1;
      } else {
        const unsigned v = (d3 == m3) ? lnv : 0u;                // max -> smallest n
        unsigned mv = v;
#pragma unroll
        for (int s = 1; s < 8; s <<= 1) {
          const unsigned o = __shfl_xor(mv, s, 64);
          mv = o > mv ? o : mv;
        }
        const ull b4 = __ballot((d3 == m3) && (v == mv)) & 0xFFull;
        src = __ffsll(b4) - 1;
      }
      // decode own record, fetch winner's fields from lane src
      const float xx = __uint_as_float((unsigned)(r1 >> 32));
      const float yy = __uint_as_float(((unsigned)((r1 >> 16) & 0xFFFFull) << 16) |
                                       (unsigned)(r2 >> 48));
      const float zz = __uint_as_float((unsigned)((r2 >> 16) & 0xFFFFFFFFull));
      const int n2   = 65535 - (int)__shfl(lnv, src, 64);
      const float wx = __shfl(xx, src, 64);
      const float wy = __shfl(yy, src, 64);
      const float wz = __shfl(zz, src, 64);
      if (lane == 0) {
        bc[0] = wx; bc[1] = wy; bc[2] = wz;
        if (w == 0) {
          out_idx[t + 1] = (float)n2;           // exact in fp32
          out_smp[(t + 1) * 3 + 0] = wx;
          out_smp[(t + 1) * 3 + 1] = wy;
          out_smp[(t + 1) * 3 + 2] = wz;
        }
      }
    } else if (wave == 1) {
      // ---- duplicate stage2; mirror publish to copy I (IF fallback) ----
      const int e = lane & 15;
      const unsigned d2 = red[e][0];
      const unsigned nn = red[e][1];
      unsigned m2 = d2;
#pragma unroll
      for (int s = 1; s < 16; s <<= 1) {
        const unsigned o = __shfl_xor(m2, s, 64);
        m2 = o > m2 ? o : m2;
      }
      const ull bb = __ballot(d2 == m2) & 0xFFFFull;
      int ewin;
      if (__popcll(bb) == 1) {
        ewin = __ffsll(bb) - 1;
      } else {
        const unsigned v = (d2 == m2) ? (65535u - nn) : 0u;
        unsigned mv = v;
#pragma unroll
        for (int s = 1; s < 16; s <<= 1) {
          const unsigned o = __shfl_xor(mv, s, 64);
          mv = o > mv ? o : mv;
        }
        const ull b2 = __ballot((d2 == m2) && (v == mv)) & 0xFFFFull;
        ewin = __ffsll(b2) - 1;
      }
      if (lane == ewin) {
        const ull k2 = ((ull)d2 << 16) | (ull)(65535u - nn);
        const unsigned xb = red[e][2], yb = red[e][3], zb = red[e][4];
        const ull w0 = (k2 << 16) | tag;
        const ull w1 = ((ull)xb << 32) | ((ull)(yb >> 16) << 16) | tag;
        const ull w2 = ((ull)(yb & 0xFFFFu) << 48) | ((ull)zb << 16) | tag;
        ull* recI = baseI + (size_t)(par * WPB + w) * RECQ;
        __hip_atomic_store(recI + 0, w0, __ATOMIC_RELAXED, __HIP_MEMORY_SCOPE_AGENT);
        __hip_atomic_store(recI + 1, w1, __ATOMIC_RELAXED, __HIP_MEMORY_SCOPE_AGENT);
        __hip_atomic_store(recI + 2, w2, __ATOMIC_RELAXED, __HIP_MEMORY_SCOPE_AGENT);
      }
    }
    __syncthreads();  // barrier2
    cx = bc[0]; cy = bc[1]; cz = bc[2];
  }
}

extern "C" void kernel_launch(void* const* d_in, const int* in_sizes, int n_in,
                              void* d_out, int out_size, void* d_ws, size_t ws_size,
                              hipStream_t stream) {
  (void)in_sizes; (void)n_in; (void)out_size; (void)ws_size;
  const float* pts = (const float*)d_in[0];
  float* out = (float*)d_out;
  ull* ws = (ull*)d_ws;
  fps_kernel<<<dim3(NB * WPB), dim3(TPB), 0, stream>>>(pts, out, ws);
}